// Round 2
// baseline (135.038 us; speedup 1.0000x reference)
//
#include <hip/hip_runtime.h>

// Problem constants
#define BB 2
#define SS 1024
#define DD 768
#define HH 128
#define LL 51

typedef float f32x4 __attribute__((ext_vector_type(4)));

// Workspace layout (floats):
//  WuV : [51][768]  @ 0
//  WwV : [51][768]  @ 39168
//  cP  : [51]       @ 78336   (Wv·(bu+bias) + bv)
//  cQ  : [51]       @ 78400   (Wv·bw)
//  P   : [2048][51] @ 78464   (row-major over b*S+i)
//  Qt  : [2][51][1024] @ 182912
#define OFF_WWV 39168
#define OFF_CP  78336
#define OFF_CQ  78400
#define OFF_P   78464
#define OFF_QT  182912

// Kernel 1: fold Wv into Wu/Ww, and fold all biases into per-l constants.
// One block per l (51 blocks), 256 threads.
__global__ __launch_bounds__(256) void fuse_weights(
    const float* __restrict__ Wu, const float* __restrict__ bu,
    const float* __restrict__ Ww, const float* __restrict__ bw,
    const float* __restrict__ Wv, const float* __restrict__ bv,
    const float* __restrict__ bias, float* __restrict__ ws) {
  __shared__ float wv[HH];
  const int l = blockIdx.x;
  const int t = threadIdx.x;
  if (t < HH) wv[t] = Wv[l * HH + t];
  __syncthreads();

  float* WuV = ws;
  float* WwV = ws + OFF_WWV;
  for (int d = t; d < DD; d += 256) {
    float au = 0.f, aw = 0.f;
#pragma unroll 8
    for (int h = 0; h < HH; ++h) {
      au += wv[h] * Wu[h * DD + d];   // coalesced across threads (fixed h)
      aw += wv[h] * Ww[h * DD + d];
    }
    WuV[l * DD + d] = au;
    WwV[l * DD + d] = aw;
  }
  if (t == 0) {
    float a = 0.f, c = 0.f;
#pragma unroll 8
    for (int h = 0; h < HH; ++h) {
      a += wv[h] * (bu[h] + bias[h]);
      c += wv[h] * bw[h];
    }
    ws[OFF_CP + l] = a + bv[l];
    ws[OFF_CQ + l] = c;
  }
}

// Kernel 2: P[row][l] = x[row]·WuV[l] + cP[l];  Qt[b][l][j] = x[row]·WwV[l] + cQ[l]
// TM=8 rows per block -> 256 blocks, 256 threads.
// Thread (c = t&127 < 102, rg = t>>7): column c over 4 rows.
#define TM 8
__global__ __launch_bounds__(256) void proj(
    const float* __restrict__ x, float* __restrict__ ws) {
  __shared__ float xs[TM * DD];  // 24 KiB
  const int t = threadIdx.x;
  const long base = (long)blockIdx.x * TM * DD;

  const f32x4* x4 = (const f32x4*)(x + base);
  f32x4* xs4 = (f32x4*)xs;
#pragma unroll
  for (int k = 0; k < (TM * DD / 4) / 256; ++k)  // 6 iters
    xs4[t + k * 256] = x4[t + k * 256];
  __syncthreads();

  const int c = t & 127;
  const int rg = t >> 7;
  if (c >= 2 * LL) return;

  const float* WuV = ws;
  const float* WwV = ws + OFF_WWV;
  const float* Wrow = (c < LL) ? (WuV + c * DD) : (WwV + (c - LL) * DD);
  const float* xrow = xs + (rg * 4) * DD;

  float acc[4] = {0.f, 0.f, 0.f, 0.f};
  for (int d = 0; d < DD; d += 4) {
    f32x4 w = *(const f32x4*)(Wrow + d);
#pragma unroll
    for (int r = 0; r < 4; ++r) {
      f32x4 xv = *(const f32x4*)(xrow + r * DD + d);  // wave-uniform -> LDS broadcast
      acc[r] += w.x * xv.x + w.y * xv.y + w.z * xv.z + w.w * xv.w;
    }
  }

  const int row0 = blockIdx.x * TM + rg * 4;
  if (c < LL) {
    const float add = ws[OFF_CP + c];
    float* P = ws + OFF_P;
#pragma unroll
    for (int r = 0; r < 4; ++r) P[(row0 + r) * LL + c] = acc[r] + add;
  } else {
    const int l = c - LL;
    const float add = ws[OFF_CQ + l];
    float* Qt = ws + OFF_QT;
#pragma unroll
    for (int r = 0; r < 4; ++r) {
      const int row = row0 + r;
      const int b = row >> 10, j = row & (SS - 1);
      Qt[((long)(b * LL + l)) * SS + j] = acc[r] + add;
    }
  }
}

// Kernel 3: out[b,i,l,j] = P[b*S+i][l] + Qt[b][l][j].  One block per (b,i) = 2048
// blocks, 256 threads; each thread writes one float4 per l (51 iterations).
__global__ __launch_bounds__(256) void expand(
    const float* __restrict__ ws, float* __restrict__ out) {
  __shared__ float pl[LL];
  const int row = blockIdx.x;  // b*S + i
  const int b = row >> 10;
  const int t = threadIdx.x;
  if (t < LL) pl[t] = ws[OFF_P + row * LL + t];
  __syncthreads();

  const f32x4* q4 = (const f32x4*)(ws + OFF_QT + (long)b * LL * SS);
  f32x4* o4 = (f32x4*)(out + (long)row * LL * SS);
#pragma unroll 3
  for (int l = 0; l < LL; ++l) {
    const float p = pl[l];
    f32x4 q = q4[l * (SS / 4) + t];
    f32x4 v = q + p;
    __builtin_nontemporal_store(v, &o4[l * (SS / 4) + t]);
  }
}

extern "C" void kernel_launch(void* const* d_in, const int* in_sizes, int n_in,
                              void* d_out, int out_size, void* d_ws, size_t ws_size,
                              hipStream_t stream) {
  const float* x    = (const float*)d_in[0];
  const float* Wu   = (const float*)d_in[1];
  const float* bu   = (const float*)d_in[2];
  const float* Ww   = (const float*)d_in[3];
  const float* bw   = (const float*)d_in[4];
  const float* Wv   = (const float*)d_in[5];
  const float* bv   = (const float*)d_in[6];
  const float* bias = (const float*)d_in[7];
  float* out = (float*)d_out;
  float* ws  = (float*)d_ws;

  fuse_weights<<<dim3(LL), dim3(256), 0, stream>>>(Wu, bu, Ww, bw, Wv, bv, bias, ws);
  proj<<<dim3((BB * SS) / TM), dim3(256), 0, stream>>>(x, ws);
  expand<<<dim3(BB * SS), dim3(256), 0, stream>>>(ws, out);
}

// Round 3
// 120.578 us; speedup vs baseline: 1.1199x; 1.1199x over previous
//
#include <hip/hip_runtime.h>

// Problem constants
#define BB 2
#define SS 1024
#define DD 768
#define HH 128
#define LL 51

typedef float f32x4 __attribute__((ext_vector_type(4)));

// Workspace layout (floats):
//  wt  : [192][128][4] @ 0       fused weights, transposed-packed:
//                                wt[d4][l][k]      = (Wv·Wu)[l][d4*4+k]
//                                wt[d4][51+l][k]   = (Wv·Ww)[l][d4*4+k]
//  cP  : [51]          @ 98304   (Wv·(bu+bias) + bv)
//  cQ  : [51]          @ 98368   (Wv·bw)
//  P   : [2048][51]    @ 98432
//  Qt  : [2][51][1024] @ 202880
#define OFF_WT 0
#define OFF_CP 98304
#define OFF_CQ 98368
#define OFF_P  98432
#define OFF_QT 202880

// Kernel 1: fold Wv into Wu/Ww (and biases into per-l constants), writing the
// transposed-packed wt layout so proj's weight reads are lane-coalesced.
// Grid 204 = 51 l × 4 d-chunks of 192 columns; 256 threads.
__global__ __launch_bounds__(256) void fuse_weights(
    const float* __restrict__ Wu, const float* __restrict__ bu,
    const float* __restrict__ Ww, const float* __restrict__ bw,
    const float* __restrict__ Wv, const float* __restrict__ bv,
    const float* __restrict__ bias, float* __restrict__ ws) {
  __shared__ float wv[HH];
  const int l  = blockIdx.x >> 2;
  const int ch = blockIdx.x & 3;
  const int t  = threadIdx.x;
  if (t < HH) wv[t] = Wv[l * HH + t];
  __syncthreads();

  if (t < 192) {
    const int d = ch * 192 + t;
    float au = 0.f, aw = 0.f;
#pragma unroll 8
    for (int h = 0; h < HH; ++h) {
      au += wv[h] * Wu[h * DD + d];   // lanes: consecutive d -> coalesced
      aw += wv[h] * Ww[h * DD + d];
    }
    float* wt = ws + OFF_WT;
    wt[((d >> 2) * 128 + l) * 4 + (d & 3)]        = au;
    wt[((d >> 2) * 128 + (LL + l)) * 4 + (d & 3)] = aw;
  }
  if (ch == 0 && t == 0) {
    float a = 0.f, cc = 0.f;
#pragma unroll 8
    for (int h = 0; h < HH; ++h) {
      a  += wv[h] * (bu[h] + bias[h]);
      cc += wv[h] * bw[h];
    }
    ws[OFF_CP + l] = a + bv[l];
    ws[OFF_CQ + l] = cc;
  }
}

// Kernel 2: P[row][l] = x[row]·WuV[l] + cP[l];  Qt[b][l][j] = x[row]·WwV[l] + cQ[l]
// TM=8 rows per block -> 256 blocks, 256 threads.
// Thread (c = t&127, rg = t>>7): output column c over 4 rows.
// Weight reads: wt[(d4*128 + c)*4 .. +3] -> 16 B/lane, lane-consecutive c ->
// fully coalesced L2 streams. x reads: LDS, wave-uniform -> broadcast.
#define TM 8
__global__ __launch_bounds__(256) void proj(
    const float* __restrict__ x, float* __restrict__ ws) {
  __shared__ float xs[TM * DD];  // 24 KiB
  const int t = threadIdx.x;
  const long base = (long)blockIdx.x * TM * DD;

  const f32x4* x4 = (const f32x4*)(x + base);
  f32x4* xs4 = (f32x4*)xs;
#pragma unroll
  for (int k = 0; k < (TM * DD / 4) / 256; ++k)  // 6 iters
    xs4[t + k * 256] = x4[t + k * 256];
  __syncthreads();

  const int c = t & 127;
  const int rg = t >> 7;
  if (c >= 2 * LL) return;

  const float* wt = ws + OFF_WT;
  const float* xrow = xs + (rg * 4) * DD;

  float acc[4] = {0.f, 0.f, 0.f, 0.f};
#pragma unroll 4
  for (int d4 = 0; d4 < DD / 4; ++d4) {
    f32x4 w = *(const f32x4*)(wt + (d4 * 128 + c) * 4);
#pragma unroll
    for (int r = 0; r < 4; ++r) {
      f32x4 xv = *(const f32x4*)(xrow + r * DD + d4 * 4);  // wave-uniform
      acc[r] += w.x * xv.x + w.y * xv.y + w.z * xv.z + w.w * xv.w;
    }
  }

  const int row0 = blockIdx.x * TM + rg * 4;
  if (c < LL) {
    const float add = ws[OFF_CP + c];
#pragma unroll
    for (int r = 0; r < 4; ++r) ws[OFF_P + (row0 + r) * LL + c] = acc[r] + add;
  } else {
    const int l = c - LL;
    const float add = ws[OFF_CQ + l];
#pragma unroll
    for (int r = 0; r < 4; ++r) {
      const int row = row0 + r;
      const int b = row >> 10, j = row & (SS - 1);
      ws[OFF_QT + ((long)(b * LL + l)) * SS + j] = acc[r] + add;
    }
  }
}

// Kernel 3: out[b,i,l,j] = P[b*S+i][l] + Qt[b][l][j].  One block per (b,i) =
// 2048 blocks, 256 threads; each thread writes one float4 per l.
__global__ __launch_bounds__(256) void expand(
    const float* __restrict__ ws, float* __restrict__ out) {
  __shared__ float pl[LL];
  const int row = blockIdx.x;  // b*S + i
  const int b = row >> 10;
  const int t = threadIdx.x;
  if (t < LL) pl[t] = ws[OFF_P + row * LL + t];
  __syncthreads();

  const f32x4* q4 = (const f32x4*)(ws + OFF_QT + (long)b * LL * SS);
  f32x4* o4 = (f32x4*)(out + (long)row * LL * SS);
#pragma unroll 4
  for (int l = 0; l < LL; ++l) {
    const float p = pl[l];
    f32x4 q = q4[l * (SS / 4) + t];
    f32x4 v = q + p;
    __builtin_nontemporal_store(v, &o4[l * (SS / 4) + t]);
  }
}

extern "C" void kernel_launch(void* const* d_in, const int* in_sizes, int n_in,
                              void* d_out, int out_size, void* d_ws, size_t ws_size,
                              hipStream_t stream) {
  const float* x    = (const float*)d_in[0];
  const float* Wu   = (const float*)d_in[1];
  const float* bu   = (const float*)d_in[2];
  const float* Ww   = (const float*)d_in[3];
  const float* bw   = (const float*)d_in[4];
  const float* Wv   = (const float*)d_in[5];
  const float* bv   = (const float*)d_in[6];
  const float* bias = (const float*)d_in[7];
  float* out = (float*)d_out;
  float* ws  = (float*)d_ws;

  fuse_weights<<<dim3(LL * 4), dim3(256), 0, stream>>>(Wu, bu, Ww, bw, Wv, bv, bias, ws);
  proj<<<dim3((BB * SS) / TM), dim3(256), 0, stream>>>(x, ws);
  expand<<<dim3(BB * SS), dim3(256), 0, stream>>>(ws, out);
}

// Round 4
// 115.705 us; speedup vs baseline: 1.1671x; 1.0421x over previous
//
#include <hip/hip_runtime.h>

// Problem constants
#define BB 2
#define SS 1024
#define DD 768
#define HH 128
#define LL 51

typedef float f32x4 __attribute__((ext_vector_type(4)));

// Workspace layout (floats):
//  wt  : [192][128][4] @ 0       fused weights, transposed-packed:
//                                wt[d4][l][k]      = (Wv·Wu)[l][d4*4+k]
//                                wt[d4][51+l][k]   = (Wv·Ww)[l][d4*4+k]
//  cP  : [51]          @ 98304   (Wv·(bu+bias) + bv)
//  cQ  : [51]          @ 98368   (Wv·bw)
//  P   : [2048][51]    @ 98432
//  Qt  : [2][51][1024] @ 202880
#define OFF_WT 0
#define OFF_CP 98304
#define OFF_CQ 98368
#define OFF_P  98432
#define OFF_QT 202880

// Kernel 1: fold Wv into Wu/Ww (and biases into per-l constants), writing the
// transposed-packed wt layout so proj's weight reads are lane-coalesced.
// Grid 204 = 51 l × 4 d-chunks of 192 columns; 256 threads.
__global__ __launch_bounds__(256) void fuse_weights(
    const float* __restrict__ Wu, const float* __restrict__ bu,
    const float* __restrict__ Ww, const float* __restrict__ bw,
    const float* __restrict__ Wv, const float* __restrict__ bv,
    const float* __restrict__ bias, float* __restrict__ ws) {
  __shared__ float wv[HH];
  const int l  = blockIdx.x >> 2;
  const int ch = blockIdx.x & 3;
  const int t  = threadIdx.x;
  if (t < HH) wv[t] = Wv[l * HH + t];
  __syncthreads();

  if (t < 192) {
    const int d = ch * 192 + t;
    float au = 0.f, aw = 0.f;
#pragma unroll 8
    for (int h = 0; h < HH; ++h) {
      au += wv[h] * Wu[h * DD + d];   // lanes: consecutive d -> coalesced
      aw += wv[h] * Ww[h * DD + d];
    }
    float* wt = ws + OFF_WT;
    wt[((d >> 2) * 128 + l) * 4 + (d & 3)]        = au;
    wt[((d >> 2) * 128 + (LL + l)) * 4 + (d & 3)] = aw;
  }
  if (ch == 0 && t == 0) {
    float a = 0.f, cc = 0.f;
#pragma unroll 8
    for (int h = 0; h < HH; ++h) {
      a  += wv[h] * (bu[h] + bias[h]);
      cc += wv[h] * bw[h];
    }
    ws[OFF_CP + l] = a + bv[l];
    ws[OFF_CQ + l] = cc;
  }
}

// Kernel 2: P[row][l] = x[row]·WuV[l] + cP[l];  Qt[b][l][j] = x[row]·WwV[l] + cQ[l]
// TM=4 rows per block -> 512 blocks (2 blocks/CU, 8 waves/CU for latency
// hiding), 256 threads. Thread (c = t&127, rg = t>>7): column c over 2 rows.
#define TM 4
__global__ __launch_bounds__(256) void proj(
    const float* __restrict__ x, float* __restrict__ ws) {
  __shared__ float xs[TM * DD];  // 12 KiB
  const int t = threadIdx.x;
  const long base = (long)blockIdx.x * TM * DD;

  const f32x4* x4 = (const f32x4*)(x + base);
  f32x4* xs4 = (f32x4*)xs;
#pragma unroll
  for (int k = 0; k < (TM * DD / 4) / 256; ++k)  // 3 iters
    xs4[t + k * 256] = x4[t + k * 256];
  __syncthreads();

  const int c = t & 127;
  const int rg = t >> 7;
  if (c >= 2 * LL) return;

  const float* wt = ws + OFF_WT;
  const float* xrow = xs + (rg * 2) * DD;

  float acc[2] = {0.f, 0.f};
#pragma unroll 4
  for (int d4 = 0; d4 < DD / 4; ++d4) {
    f32x4 w = *(const f32x4*)(wt + (d4 * 128 + c) * 4);  // lane-coalesced L2
#pragma unroll
    for (int r = 0; r < 2; ++r) {
      f32x4 xv = *(const f32x4*)(xrow + r * DD + d4 * 4);  // wave-uniform
      acc[r] += w.x * xv.x + w.y * xv.y + w.z * xv.z + w.w * xv.w;
    }
  }

  const int row0 = blockIdx.x * TM + rg * 2;
  if (c < LL) {
    const float add = ws[OFF_CP + c];
#pragma unroll
    for (int r = 0; r < 2; ++r) ws[OFF_P + (row0 + r) * LL + c] = acc[r] + add;
  } else {
    const int l = c - LL;
    const float add = ws[OFF_CQ + l];
#pragma unroll
    for (int r = 0; r < 2; ++r) {
      const int row = row0 + r;
      const int b = row >> 10, j = row & (SS - 1);
      ws[OFF_QT + ((long)(b * LL + l)) * SS + j] = acc[r] + add;
    }
  }
}

// Kernel 3: out[b,i,l,j] = P[b*S+i][l] + Qt[b][l][j].
// RB=4 rows per block -> 512 blocks, 256 threads. Each block reads Qt[b]
// ONCE for 4 output rows (L2 read traffic /4) and issues 4 independent NT
// store streams per l-iteration (write-side MLP).
#define RB 4
__global__ __launch_bounds__(256) void expand(
    const float* __restrict__ ws, float* __restrict__ out) {
  __shared__ float pls[LL * RB];  // pls[l*4+r] = P[row0+r][l], packed for b128 broadcast
  const int row0 = blockIdx.x * RB;  // RB | SS so one b per block
  const int b = row0 >> 10;
  const int t = threadIdx.x;
  if (t < LL * RB) {
    const int l = t >> 2, r = t & 3;
    pls[t] = ws[OFF_P + (row0 + r) * LL + l];
  }
  __syncthreads();

  const f32x4* q4 = (const f32x4*)(ws + OFF_QT + (long)b * LL * SS);
  float* obase = out + (long)row0 * LL * SS;
#pragma unroll 3
  for (int l = 0; l < LL; ++l) {
    f32x4 q = q4[l * (SS / 4) + t];                    // L2-resident
    f32x4 p4 = *(const f32x4*)(&pls[l * RB]);          // LDS broadcast, 16 B
    f32x4 v0 = q + p4.x;
    f32x4 v1 = q + p4.y;
    f32x4 v2 = q + p4.z;
    f32x4 v3 = q + p4.w;
    f32x4* o0 = (f32x4*)(obase + (long)l * SS) + t;
    __builtin_nontemporal_store(v0, o0);
    __builtin_nontemporal_store(v1, o0 + (1 * LL * SS) / 4);
    __builtin_nontemporal_store(v2, o0 + (2 * LL * SS) / 4);
    __builtin_nontemporal_store(v3, o0 + (3 * LL * SS) / 4);
  }
}

extern "C" void kernel_launch(void* const* d_in, const int* in_sizes, int n_in,
                              void* d_out, int out_size, void* d_ws, size_t ws_size,
                              hipStream_t stream) {
  const float* x    = (const float*)d_in[0];
  const float* Wu   = (const float*)d_in[1];
  const float* bu   = (const float*)d_in[2];
  const float* Ww   = (const float*)d_in[3];
  const float* bw   = (const float*)d_in[4];
  const float* Wv   = (const float*)d_in[5];
  const float* bv   = (const float*)d_in[6];
  const float* bias = (const float*)d_in[7];
  float* out = (float*)d_out;
  float* ws  = (float*)d_ws;

  fuse_weights<<<dim3(LL * 4), dim3(256), 0, stream>>>(Wu, bu, Ww, bw, Wv, bv, bias, ws);
  proj<<<dim3((BB * SS) / TM), dim3(256), 0, stream>>>(x, ws);
  expand<<<dim3((BB * SS) / RB), dim3(256), 0, stream>>>(ws, out);
}